// Round 1
// baseline (660.063 us; speedup 1.0000x reference)
//
#include <hip/hip_runtime.h>

#define NB 2
#define NH 12
#define NS 256
#define NE 64
#define NC 768   // NH*NE
#define NL 25

// out[b,j,l,i] = bias[l] + sum_{k,e} p[b,k,i,j] * (v[b,k,j,e] + rel[b,i,j,k*64+e]) * W[l,k*64+e]
__global__ __launch_bounds__(320) void tmhs_main(
    const float* __restrict__ p,    // (B,H,S,S)
    const float* __restrict__ v,    // (B,H,S,E)
    const float* __restrict__ rel,  // (B,S,S,C)
    const float* __restrict__ W,    // (L,C)
    const float* __restrict__ bias, // (L,)
    float* __restrict__ out)        // (B,S,L,S)
{
    // sR row stride 68 floats = 272 B: 16B-aligned rows, and b128 reads by
    // lane i hit banks 4(i+e4)..+3 -> each 8-lane group sweeps all 32 banks
    // exactly once: conflict-free at the b128 throughput limit.
    __shared__ float sR[64][68];    // rel+v tile for current head chunk (17.4 KB)
    __shared__ float sW[NL][64];    // W chunk for current head (6.4 KB)
    __shared__ float sP[64];        // p[b,k,i0..i0+63,j]
    __shared__ float sBias[NL];

    const int tid = threadIdx.x;
    const int bx  = blockIdx.x;
    const int it  = bx & 3;          // i-tile (4 tiles of 64)
    const int j   = (bx >> 2) & 255;
    const int b   = bx >> 10;
    const int i0  = it * 64;

    if (tid < NL) sBias[tid] = bias[tid];

    const int i_local = tid & 63;
    const int wv = tid >> 6;         // wave 0..4
    const int l0 = wv * 5;           // 5 labels per wave -> 25 total

    float acc[5] = {0.f, 0.f, 0.f, 0.f, 0.f};

    for (int k = 0; k < NH; ++k) {
        __syncthreads();  // protect sR/sW/sP from previous iteration's readers
        if (tid < 256) {
            // stage (rel + v) tile: 64 rows x 64 floats; 4 threads/row, 4 float4 each
            const int row  = tid >> 2;
            const int part = tid & 3;
            const float4* vs = (const float4*)(v + (((b*NH + k)*NS + j) << 6) + part*16);
            const float4* rs = (const float4*)(rel + (((b*NS + (i0+row))*NS + j)*NC + k*64 + part*16));
            float4* dst = (float4*)(&sR[row][part*16]);
            float4 a0 = rs[0], a1 = rs[1], a2 = rs[2], a3 = rs[3];
            const float4 b0 = vs[0], b1 = vs[1], b2 = vs[2], b3 = vs[3];
            a0.x += b0.x; a0.y += b0.y; a0.z += b0.z; a0.w += b0.w;
            a1.x += b1.x; a1.y += b1.y; a1.z += b1.z; a1.w += b1.w;
            a2.x += b2.x; a2.y += b2.y; a2.z += b2.z; a2.w += b2.w;
            a3.x += b3.x; a3.y += b3.y; a3.z += b3.z; a3.w += b3.w;
            dst[0] = a0; dst[1] = a1; dst[2] = a2; dst[3] = a3;
        } else {
            const int t = tid - 256;  // 0..63 (wave 4)
            // p gather: stride-1KB 4B loads; p is 6.3 MB -> L3-resident, no HBM overfetch
            sP[t] = p[((b*NH + k)*NS + (i0 + t))*NS + j];
            // W chunk: 25 rows x 16 float4 = 400 float4 across 64 threads
            for (int q = t; q < NL*16; q += 64) {
                ((float4*)sW)[q] = *((const float4*)(W + (q >> 4)*NC + k*64 + ((q & 15) << 2)));
            }
        }
        __syncthreads();

        const float pk = sP[i_local];
        float racc[5] = {0.f, 0.f, 0.f, 0.f, 0.f};
        #pragma unroll
        for (int e4 = 0; e4 < 16; ++e4) {
            const float4 r4 = *((const float4*)(&sR[i_local][e4*4]));
            #pragma unroll
            for (int u = 0; u < 5; ++u) {
                const float4 w4 = *((const float4*)(&sW[l0 + u][e4*4]));  // wave-uniform -> broadcast
                racc[u] = fmaf(r4.x, w4.x, racc[u]);
                racc[u] = fmaf(r4.y, w4.y, racc[u]);
                racc[u] = fmaf(r4.z, w4.z, racc[u]);
                racc[u] = fmaf(r4.w, w4.w, racc[u]);
            }
        }
        #pragma unroll
        for (int u = 0; u < 5; ++u) acc[u] = fmaf(pk, racc[u], acc[u]);
    }

    // coalesced epilogue: lane -> i contiguous in out[b,j,l,i]
    const int obase = ((b*NS + j)*NL)*NS + i0 + i_local;
    #pragma unroll
    for (int u = 0; u < 5; ++u) {
        out[obase + (l0 + u)*NS] = acc[u] + sBias[l0 + u];
    }
}

extern "C" void kernel_launch(void* const* d_in, const int* in_sizes, int n_in,
                              void* d_out, int out_size, void* d_ws, size_t ws_size,
                              hipStream_t stream) {
    const float* p    = (const float*)d_in[0];
    const float* v    = (const float*)d_in[1];
    const float* rel  = (const float*)d_in[2];
    const float* W    = (const float*)d_in[3];
    const float* bias = (const float*)d_in[4];
    float* out = (float*)d_out;
    tmhs_main<<<dim3(NB * NS * 4), dim3(320), 0, stream>>>(p, v, rel, W, bias, out);
}